// Round 2
// baseline (2920.221 us; speedup 1.0000x reference)
//
#include <hip/hip_runtime.h>
#include <hip/hip_bf16.h>
#include <math.h>

#define NFEAT 500
#define NHID  256
#define NCLS  64
#define KPOLY 10

// ------------------------- weight transposes -------------------------
__global__ void transpose_w1(const float* __restrict__ W1, float* __restrict__ W1T) {
  int idx = blockIdx.x * blockDim.x + threadIdx.x;   // W1T[k*256 + h] = W1[h*500 + k]
  if (idx >= NFEAT * NHID) return;
  int k = idx / NHID, h = idx % NHID;
  W1T[idx] = W1[h * NFEAT + k];
}
__global__ void transpose_w2(const float* __restrict__ W2, float* __restrict__ W2T) {
  int idx = blockIdx.x * blockDim.x + threadIdx.x;   // W2T[k*64 + c] = W2[c*256 + k]
  if (idx >= NHID * NCLS) return;
  int k = idx / NCLS, c = idx % NCLS;
  W2T[idx] = W2[c * NHID + k];
}

// ------------------------- CSR build -------------------------
__global__ void edge_count(const int* __restrict__ ei, int E,
                           int* __restrict__ deg, int* __restrict__ cnt) {
  int stride = gridDim.x * blockDim.x;
  for (int e = blockIdx.x * blockDim.x + threadIdx.x; e < E; e += stride) {
    int r = ei[e], c = ei[E + e];
    atomicAdd(&cnt[r], 1);              // all edges go in CSR (self-loops get w=0)
    if (r != c) atomicAdd(&deg[r], 1);  // valid-degree for Laplacian
  }
}

__global__ void make_dinv(const int* __restrict__ deg, float* __restrict__ dinv, int n) {
  int i = blockIdx.x * blockDim.x + threadIdx.x;
  if (i < n) {
    int d = deg[i];
    dinv[i] = (d > 0) ? rsqrtf((float)d) : 0.0f;
  }
}

__global__ void scan_block(const int* __restrict__ cnt, int* __restrict__ rowptr,
                           int* __restrict__ bsums, int n) {
  __shared__ int s[256];
  int i = blockIdx.x * 256 + threadIdx.x;
  int v = (i < n) ? cnt[i] : 0;
  s[threadIdx.x] = v;
  __syncthreads();
  for (int off = 1; off < 256; off <<= 1) {
    int t = (threadIdx.x >= (unsigned)off) ? s[threadIdx.x - off] : 0;
    __syncthreads();
    s[threadIdx.x] += t;
    __syncthreads();
  }
  if (i < n) rowptr[i + 1] = s[threadIdx.x];
  if (threadIdx.x == 255) bsums[blockIdx.x] = s[255];
}

__global__ void scan_sums(int* __restrict__ bsums, int nb, int* __restrict__ rowptr) {
  if (threadIdx.x == 0 && blockIdx.x == 0) {
    int run = 0;
    for (int b = 0; b < nb; ++b) { int t = bsums[b]; bsums[b] = run; run += t; }
    rowptr[0] = 0;
  }
}

__global__ void scan_add(int* __restrict__ rowptr, const int* __restrict__ bsums, int n) {
  int i = blockIdx.x * 256 + threadIdx.x;
  if (i < n) rowptr[i + 1] += bsums[i >> 8];
}

__global__ void scatter_edges(const int* __restrict__ ei, int E,
                              const float* __restrict__ dinv,
                              const int* __restrict__ rowptr, int* __restrict__ cur,
                              int* __restrict__ colc, float* __restrict__ wcsr) {
  int stride = gridDim.x * blockDim.x;
  for (int e = blockIdx.x * blockDim.x + threadIdx.x; e < E; e += stride) {
    int r = ei[e], c = ei[E + e];
    int pos = rowptr[r] + atomicAdd(&cur[r], 1);
    colc[pos] = c;
    wcsr[pos] = (r != c) ? (-dinv[r] * dinv[c]) : 0.0f;
  }
}

// ------------------------- fused MLP: h2 = relu(x@W1^T)@W2^T -------------------------
// 64 rows x 256 hid per 256-thread block; 8x8 register tile per thread.
// GEMM1: 64 FMA per 4 ds_read_b128. GEMM2: float4 k-quads.
__global__ __launch_bounds__(256, 2) void mlp_fused64(
    const float* __restrict__ x, const float* __restrict__ W1T,
    const float* __restrict__ W2T, float* __restrict__ h2, int n)
{
  __shared__ float hs[64][260];                 // relu(h); 260*4=1040 is 16B-mult
  __shared__ union {
    struct {
      float xs_t[8][72];                        // x chunk transposed [k][row]; 72*4=288 16B-mult
      float ws1[8][256];                        // W1T chunk [k][hid]
    } g1;
    float w2s[32][68];                          // W2T chunk [k][cls]; 68*4=272 16B-mult
  } u;

  const int tid = threadIdx.x;
  const int tx = tid & 31;            // hid group: 8 hiddens (c0 = tx*8)
  const int ty = tid >> 5;            // row group: 8 rows   (r0 = ty*8)
  const int row0 = blockIdx.x * 64;

  float acc[8][8];
#pragma unroll
  for (int i = 0; i < 8; ++i)
#pragma unroll
    for (int j = 0; j < 8; ++j) acc[i][j] = 0.0f;

  // ---- GEMM1: K in chunks of 8 (63 chunks, last half-padded with zeros) ----
  for (int ck = 0; ck < 63; ++ck) {
    const int k0 = ck * 8;
    // stage x tile 64x8, transposed into xs_t[k][row] (threads 0..127)
    if (tid < 128) {
      int r = tid >> 1, half = tid & 1;
      int gr = row0 + r, gk = k0 + half * 4;
      float4 v = make_float4(0.f, 0.f, 0.f, 0.f);
      if (gr < n && gk < NFEAT)                 // NFEAT%4==0 so gk<500 => full float4 valid
        v = *(const float4*)&x[(size_t)gr * NFEAT + gk];
      int kb = half * 4;
      u.g1.xs_t[kb + 0][r] = v.x;
      u.g1.xs_t[kb + 1][r] = v.y;
      u.g1.xs_t[kb + 2][r] = v.z;
      u.g1.xs_t[kb + 3][r] = v.w;
    }
    // stage W1T tile 8x256 (2 float4 per thread, coalesced)
#pragma unroll
    for (int s = 0; s < 2; ++s) {
      int f = tid + s * 256;                    // float4 index 0..511
      int j = f >> 6, pos = (f & 63) << 2;
      int gk = k0 + j;
      float4 wv = make_float4(0.f, 0.f, 0.f, 0.f);
      if (gk < NFEAT) wv = *(const float4*)&W1T[(size_t)gk * NHID + pos];
      *(float4*)&u.g1.ws1[j][pos] = wv;
    }
    __syncthreads();

#pragma unroll
    for (int kk = 0; kk < 8; ++kk) {
      float4 a0 = *(const float4*)&u.g1.xs_t[kk][ty * 8];
      float4 a1 = *(const float4*)&u.g1.xs_t[kk][ty * 8 + 4];
      float4 b0 = *(const float4*)&u.g1.ws1[kk][tx * 8];
      float4 b1 = *(const float4*)&u.g1.ws1[kk][tx * 8 + 4];
      float a[8] = {a0.x, a0.y, a0.z, a0.w, a1.x, a1.y, a1.z, a1.w};
      float b[8] = {b0.x, b0.y, b0.z, b0.w, b1.x, b1.y, b1.z, b1.w};
#pragma unroll
      for (int i = 0; i < 8; ++i)
#pragma unroll
        for (int j = 0; j < 8; ++j) acc[i][j] = fmaf(a[i], b[j], acc[i][j]);
    }
    __syncthreads();
  }

  // ---- relu -> hs (row-major), vectorized writes ----
#pragma unroll
  for (int i = 0; i < 8; ++i) {
    int r = ty * 8 + i;
#pragma unroll
    for (int j4 = 0; j4 < 2; ++j4) {
      float4 v;
      v.x = fmaxf(acc[i][j4 * 4 + 0], 0.f);
      v.y = fmaxf(acc[i][j4 * 4 + 1], 0.f);
      v.z = fmaxf(acc[i][j4 * 4 + 2], 0.f);
      v.w = fmaxf(acc[i][j4 * 4 + 3], 0.f);
      *(float4*)&hs[r][tx * 8 + j4 * 4] = v;
    }
  }
  __syncthreads();

  // ---- GEMM2: out[64][64] = hs @ W2T ----
  const int rg = tid >> 5;            // 8 rows (r0 = rg*8)
  const int cg = tid & 31;            // 2 classes (c0 = cg*2)
  const int r0 = rg * 8, c0 = cg * 2;
  float o[8][2];
#pragma unroll
  for (int i = 0; i < 8; ++i) { o[i][0] = 0.f; o[i][1] = 0.f; }

  for (int kb = 0; kb < NHID; kb += 32) {
    // stage w2s 32x64 (2 float4 per thread)
#pragma unroll
    for (int s = 0; s < 2; ++s) {
      int f = tid + s * 256;                    // float4 index 0..511
      int j = f >> 4, pos = (f & 15) << 2;
      *(float4*)&u.w2s[j][pos] = *(const float4*)&W2T[(size_t)(kb + j) * NCLS + pos];
    }
    __syncthreads();

#pragma unroll
    for (int q = 0; q < 8; ++q) {               // k-quads: kk = q*4 .. +4
      int kk = q * 4;
      float4 a4[8];
#pragma unroll
      for (int i = 0; i < 8; ++i)
        a4[i] = *(const float4*)&hs[r0 + i][kb + kk];   // broadcast across lanes
      float2 bq[4];
#pragma unroll
      for (int t = 0; t < 4; ++t)
        bq[t] = *(const float2*)&u.w2s[kk + t][c0];
#pragma unroll
      for (int i = 0; i < 8; ++i) {
        o[i][0] = fmaf(a4[i].x, bq[0].x, o[i][0]); o[i][1] = fmaf(a4[i].x, bq[0].y, o[i][1]);
        o[i][0] = fmaf(a4[i].y, bq[1].x, o[i][0]); o[i][1] = fmaf(a4[i].y, bq[1].y, o[i][1]);
        o[i][0] = fmaf(a4[i].z, bq[2].x, o[i][0]); o[i][1] = fmaf(a4[i].z, bq[2].y, o[i][1]);
        o[i][0] = fmaf(a4[i].w, bq[3].x, o[i][0]); o[i][1] = fmaf(a4[i].w, bq[3].y, o[i][1]);
      }
    }
    __syncthreads();
  }

#pragma unroll
  for (int i = 0; i < 8; ++i) {
    int r = row0 + r0 + i;
    if (r < n) {
      float2 v = make_float2(o[i][0], o[i][1]);
      *(float2*)&h2[(size_t)r * NCLS + c0] = v;
    }
  }
}

// ------------------------- SpMM (wave per row, lane = channel) -------------------------
__global__ void spmm_first(const int* __restrict__ rowptr, const int* __restrict__ colc,
                           const float* __restrict__ wcsr, const float* __restrict__ h,
                           float* __restrict__ tx1, float* __restrict__ acc,
                           const float* __restrict__ cw, int n) {
  int wid = (blockIdx.x * blockDim.x + threadIdx.x) >> 6;
  int lane = threadIdx.x & 63;
  if (wid >= n) return;
  int e0 = rowptr[wid], e1 = rowptr[wid + 1];
  float s = 0.0f;
  for (int e = e0; e < e1; ++e) {
    int c = colc[e];
    float wt = wcsr[e];
    s = fmaf(wt, h[(size_t)c * NCLS + lane], s);
  }
  size_t idx = (size_t)wid * NCLS + lane;
  tx1[idx] = s;
  acc[idx] = cw[0] * h[idx] + cw[1] * s;
}

__global__ void spmm_step(const int* __restrict__ rowptr, const int* __restrict__ colc,
                          const float* __restrict__ wcsr, const float* __restrict__ curb,
                          const float* __restrict__ prevb, float* __restrict__ nextb,
                          float* __restrict__ acc, const float* __restrict__ cw,
                          int k, int n) {
  int wid = (blockIdx.x * blockDim.x + threadIdx.x) >> 6;
  int lane = threadIdx.x & 63;
  if (wid >= n) return;
  int e0 = rowptr[wid], e1 = rowptr[wid + 1];
  float s = 0.0f;
  for (int e = e0; e < e1; ++e) {
    int c = colc[e];
    float wt = wcsr[e];
    s = fmaf(wt, curb[(size_t)c * NCLS + lane], s);
  }
  size_t idx = (size_t)wid * NCLS + lane;
  float t2 = 2.0f * s - prevb[idx];
  nextb[idx] = t2;
  acc[idx] += cw[k] * t2;
}

// ------------------------- log-softmax over 64 classes (in-place) -------------------------
__global__ void log_softmax_k(float* __restrict__ io, int n) {
  int wid = (blockIdx.x * blockDim.x + threadIdx.x) >> 6;
  int lane = threadIdx.x & 63;
  if (wid >= n) return;
  size_t idx = (size_t)wid * NCLS + lane;
  float v = io[idx];
  float m = v;
#pragma unroll
  for (int off = 32; off > 0; off >>= 1) m = fmaxf(m, __shfl_xor(m, off, 64));
  float ex = expf(v - m);
  float ssum = ex;
#pragma unroll
  for (int off = 32; off > 0; off >>= 1) ssum += __shfl_xor(ssum, off, 64);
  io[idx] = v - m - logf(ssum);
}

// ------------------------- launch -------------------------
extern "C" void kernel_launch(void* const* d_in, const int* in_sizes, int n_in,
                              void* d_out, int out_size, void* d_ws, size_t ws_size,
                              hipStream_t stream) {
  const float* x  = (const float*)d_in[0];
  const int*   ei = (const int*)d_in[1];
  const float* W1 = (const float*)d_in[2];
  const float* W2 = (const float*)d_in[3];
  const float* cw = (const float*)d_in[4];
  float* out = (float*)d_out;

  const int n = in_sizes[0] / NFEAT;     // 100000
  const int E = in_sizes[1] / 2;         // 1600000

  // workspace carve-up (256B aligned)
  size_t off = 0;
  auto alloc = [&](size_t bytes) { size_t o = off; off += (bytes + 255) & ~(size_t)255; return o; };
  char* w = (char*)d_ws;
  size_t o_deg   = alloc((size_t)n * 4);
  size_t o_cnt   = alloc((size_t)n * 4);
  size_t o_cur   = alloc((size_t)n * 4);
  size_t o_dinv  = alloc((size_t)n * 4);
  size_t o_rp    = alloc((size_t)(n + 1) * 4);
  size_t o_bs    = alloc(4096 * 4);
  size_t o_w1t   = alloc((size_t)NFEAT * NHID * 4);
  size_t o_w2t   = alloc((size_t)NHID * NCLS * 4);
  size_t o_colc  = alloc((size_t)E * 4);
  size_t o_wcsr  = alloc((size_t)E * 4);
  size_t o_bufH  = alloc((size_t)n * NCLS * 4);
  size_t o_bufA  = alloc((size_t)n * NCLS * 4);
  size_t o_bufB  = alloc((size_t)n * NCLS * 4);

  int*   deg    = (int*)(w + o_deg);
  int*   cnt    = (int*)(w + o_cnt);
  int*   curi   = (int*)(w + o_cur);
  float* dinv   = (float*)(w + o_dinv);
  int*   rowptr = (int*)(w + o_rp);
  int*   bsums  = (int*)(w + o_bs);
  float* W1T    = (float*)(w + o_w1t);
  float* W2T    = (float*)(w + o_w2t);
  int*   colc   = (int*)(w + o_colc);
  float* wcsr   = (float*)(w + o_wcsr);
  float* bufH   = (float*)(w + o_bufH);
  float* bufA   = (float*)(w + o_bufA);
  float* bufB   = (float*)(w + o_bufB);

  // zero deg/cnt/cur (contiguous region incl. padding)
  hipMemsetAsync(w + o_deg, 0, o_dinv - o_deg, stream);

  const int nb = (n + 255) / 256;

  transpose_w1<<<(NFEAT * NHID + 255) / 256, 256, 0, stream>>>(W1, W1T);
  transpose_w2<<<(NHID * NCLS + 255) / 256, 256, 0, stream>>>(W2, W2T);

  edge_count<<<1024, 256, 0, stream>>>(ei, E, deg, cnt);
  make_dinv<<<nb, 256, 0, stream>>>(deg, dinv, n);
  scan_block<<<nb, 256, 0, stream>>>(cnt, rowptr, bsums, n);
  scan_sums<<<1, 1, 0, stream>>>(bsums, nb, rowptr);
  scan_add<<<nb, 256, 0, stream>>>(rowptr, bsums, n);
  scatter_edges<<<1024, 256, 0, stream>>>(ei, E, dinv, rowptr, curi, colc, wcsr);

  mlp_fused64<<<(n + 63) / 64, 256, 0, stream>>>(x, W1T, W2T, bufH, n);

  const int spmm_blocks = (n + 3) / 4;   // 4 waves per 256-thread block
  spmm_first<<<spmm_blocks, 256, 0, stream>>>(rowptr, colc, wcsr, bufH, bufA, out, cw, n);

  float* P = bufH;  // Tx_{k-2}
  float* C = bufA;  // Tx_{k-1}
  float* N = bufB;  // Tx_k (to write)
  for (int k = 2; k <= KPOLY; ++k) {
    spmm_step<<<spmm_blocks, 256, 0, stream>>>(rowptr, colc, wcsr, C, P, N, out, cw, k, n);
    float* t = P; P = C; C = N; N = t;
  }

  log_softmax_k<<<spmm_blocks, 256, 0, stream>>>(out, n);
}

// Round 3
// 1961.129 us; speedup vs baseline: 1.4891x; 1.4891x over previous
//
#include <hip/hip_runtime.h>
#include <hip/hip_bf16.h>
#include <math.h>

#define NFEAT 500
#define KPAD  512
#define NHID  256
#define NCLS  64
#define KPOLY 10

typedef __attribute__((ext_vector_type(8))) short short8;
typedef __attribute__((ext_vector_type(4))) float f32x4;

__device__ inline unsigned short bf16_rn(float v) {
  unsigned u = __float_as_uint(v);
  return (unsigned short)((u + 0x7FFFu + ((u >> 16) & 1u)) >> 16);
}
__device__ inline void split2(float v, unsigned short& hi, unsigned short& lo) {
  unsigned short h = bf16_rn(v);
  float vh = __uint_as_float(((unsigned)h) << 16);
  lo = bf16_rn(v - vh);
  hi = h;
}

// ---------- weight pre-conversion into MFMA fragment layout ----------
// W1F[kg][c][kin] (kg<64, c<256, kin<8), value = W1^T[k][c] = W1[c*500+k], zero-pad k>=500
__global__ void conv_w1f(const float* __restrict__ W1, unsigned short* __restrict__ Fh,
                         unsigned short* __restrict__ Fl) {
  int i = blockIdx.x * 256 + threadIdx.x;
  if (i >= KPAD * NHID) return;
  int kg = i >> 11, c = (i >> 3) & 255, kin = i & 7;
  int k = kg * 8 + kin;
  float v = (k < NFEAT) ? W1[c * NFEAT + k] : 0.0f;
  unsigned short h, l;
  split2(v, h, l);
  Fh[i] = h; Fl[i] = l;
}
// W2F[kg][c][kin] (kg<32, c<64), value = W2^T[k][c] = W2[c*256+k], single bf16
__global__ void conv_w2f(const float* __restrict__ W2, unsigned short* __restrict__ F) {
  int i = blockIdx.x * 256 + threadIdx.x;
  if (i >= NHID * NCLS) return;
  int kg = i >> 9, c = (i >> 3) & 63, kin = i & 7;
  int k = kg * 8 + kin;
  F[i] = bf16_rn(W2[c * NHID + k]);
}

// ------------------------- CSR build -------------------------
__global__ void edge_count(const int* __restrict__ ei, int E,
                           int* __restrict__ deg, int* __restrict__ cnt) {
  int stride = gridDim.x * blockDim.x;
  for (int e = blockIdx.x * blockDim.x + threadIdx.x; e < E; e += stride) {
    int r = ei[e], c = ei[E + e];
    atomicAdd(&cnt[r], 1);
    if (r != c) atomicAdd(&deg[r], 1);
  }
}

__global__ void make_dinv(const int* __restrict__ deg, float* __restrict__ dinv, int n) {
  int i = blockIdx.x * blockDim.x + threadIdx.x;
  if (i < n) {
    int d = deg[i];
    dinv[i] = (d > 0) ? rsqrtf((float)d) : 0.0f;
  }
}

__global__ void scan_block(const int* __restrict__ cnt, int* __restrict__ rowptr,
                           int* __restrict__ bsums, int n) {
  __shared__ int s[256];
  int i = blockIdx.x * 256 + threadIdx.x;
  int v = (i < n) ? cnt[i] : 0;
  s[threadIdx.x] = v;
  __syncthreads();
  for (int off = 1; off < 256; off <<= 1) {
    int t = (threadIdx.x >= (unsigned)off) ? s[threadIdx.x - off] : 0;
    __syncthreads();
    s[threadIdx.x] += t;
    __syncthreads();
  }
  if (i < n) rowptr[i + 1] = s[threadIdx.x];
  if (threadIdx.x == 255) bsums[blockIdx.x] = s[255];
}

__global__ void scan_sums(int* __restrict__ bsums, int nb, int* __restrict__ rowptr) {
  if (threadIdx.x == 0 && blockIdx.x == 0) {
    int run = 0;
    for (int b = 0; b < nb; ++b) { int t = bsums[b]; bsums[b] = run; run += t; }
    rowptr[0] = 0;
  }
}

__global__ void scan_add(int* __restrict__ rowptr, const int* __restrict__ bsums, int n) {
  int i = blockIdx.x * 256 + threadIdx.x;
  if (i < n) rowptr[i + 1] += bsums[i >> 8];
}

__global__ void scatter_edges(const int* __restrict__ ei, int E,
                              const float* __restrict__ dinv,
                              const int* __restrict__ rowptr, int* __restrict__ cur,
                              int* __restrict__ colc, float* __restrict__ wcsr) {
  int stride = gridDim.x * blockDim.x;
  for (int e = blockIdx.x * blockDim.x + threadIdx.x; e < E; e += stride) {
    int r = ei[e], c = ei[E + e];
    int pos = rowptr[r] + atomicAdd(&cur[r], 1);
    colc[pos] = c;
    wcsr[pos] = (r != c) ? (-dinv[r] * dinv[c]) : 0.0f;
  }
}

// ------------------------- fused MLP via MFMA (bf16 hi/lo split) -------------------------
// Block: 256 thr = 4 waves; 64 rows x 256 hid; wave w owns hid-cols [64w,64w+64).
// GEMM1: h = x @ W1^T, 3-term split MFMA (fp32-class). GEMM2: h2 = relu(h) @ W2^T, single bf16.
// All LDS fragment buffers use [kgroup][row][8] subtiled layout -> ds_read_b128 conflict-free.
__global__ __launch_bounds__(256, 2) void mlp_mfma(
    const float* __restrict__ x, const unsigned short* __restrict__ W1Fh,
    const unsigned short* __restrict__ W1Fl, const unsigned short* __restrict__ W2F,
    float* __restrict__ hout, int n)
{
  __shared__ union {
    struct {
      unsigned short Ah[4][64][8], Al[4][64][8];     // 4KB + 4KB
      unsigned short Bh[4][256][8], Bl[4][256][8];   // 16KB + 16KB
    } g1;                                            // 40KB
    struct {
      unsigned short A2[32][64][8];                  // 32KB  (relu(h) bf16, frag layout)
      unsigned short B2[32][64][8];                  // 32KB  (W2 frag)
    } g2;                                            // 64KB
  } u;

  const int tid = threadIdx.x;
  const int w = tid >> 6;
  const int l = tid & 63;
  const int l15 = l & 15, l4 = l >> 4;
  const int row0 = blockIdx.x * 64;

  f32x4 acc[4][4];
  const f32x4 zf = {0.0f, 0.0f, 0.0f, 0.0f};
#pragma unroll
  for (int i = 0; i < 4; ++i)
#pragma unroll
    for (int j = 0; j < 4; ++j) acc[i][j] = zf;

  // ---- GEMM1 K-loop: 16 steps of K=32 ----
  for (int t = 0; t < 16; ++t) {
    const int k0 = t * 32;
    // stage A: x[row0..+64][k0..k0+32) fp32 -> split bf16 hi/lo into [4][64][8]
#pragma unroll
    for (int s = 0; s < 2; ++s) {
      int f = tid + s * 256;              // 0..511 : r = f>>3, slot = f&7
      int r = f >> 3, slot = f & 7;
      int gr = row0 + r, gk = k0 + slot * 4;
      float4 v = make_float4(0.f, 0.f, 0.f, 0.f);
      if (gr < n && gk + 3 < NFEAT)       // NFEAT%4==0 -> float4 fully valid or fully pad
        v = *(const float4*)&x[(size_t)gr * NFEAT + gk];
      unsigned short a0, a1, a2, a3, b0, b1, b2, b3;
      split2(v.x, a0, b0); split2(v.y, a1, b1); split2(v.z, a2, b2); split2(v.w, a3, b3);
      int kg = slot >> 1, kin0 = (slot & 1) * 4;
      *(uint2*)&u.g1.Ah[kg][r][kin0] =
          make_uint2((unsigned)a0 | ((unsigned)a1 << 16), (unsigned)a2 | ((unsigned)a3 << 16));
      *(uint2*)&u.g1.Al[kg][r][kin0] =
          make_uint2((unsigned)b0 | ((unsigned)b1 << 16), (unsigned)b2 | ((unsigned)b3 << 16));
    }
    // stage B: pre-converted frag layout, contiguous 16KB hi + 16KB lo
    {
      const uint4* gh = (const uint4*)(W1Fh + (size_t)t * 8192);
      const uint4* gl = (const uint4*)(W1Fl + (size_t)t * 8192);
      uint4* dh = (uint4*)&u.g1.Bh[0][0][0];
      uint4* dl = (uint4*)&u.g1.Bl[0][0][0];
#pragma unroll
      for (int s = 0; s < 4; ++s) { int f = tid + s * 256; dh[f] = gh[f]; dl[f] = gl[f]; }
    }
    __syncthreads();

    short8 aH[4], aL[4], bH[4], bL[4];
#pragma unroll
    for (int mf = 0; mf < 4; ++mf) {
      aH[mf] = *(const short8*)&u.g1.Ah[l4][mf * 16 + l15][0];
      aL[mf] = *(const short8*)&u.g1.Al[l4][mf * 16 + l15][0];
    }
#pragma unroll
    for (int nf = 0; nf < 4; ++nf) {
      bH[nf] = *(const short8*)&u.g1.Bh[l4][w * 64 + nf * 16 + l15][0];
      bL[nf] = *(const short8*)&u.g1.Bl[l4][w * 64 + nf * 16 + l15][0];
    }
#pragma unroll
    for (int mf = 0; mf < 4; ++mf)
#pragma unroll
      for (int nf = 0; nf < 4; ++nf) {
        acc[mf][nf] = __builtin_amdgcn_mfma_f32_16x16x32_bf16(aH[mf], bH[nf], acc[mf][nf], 0, 0, 0);
        acc[mf][nf] = __builtin_amdgcn_mfma_f32_16x16x32_bf16(aH[mf], bL[nf], acc[mf][nf], 0, 0, 0);
        acc[mf][nf] = __builtin_amdgcn_mfma_f32_16x16x32_bf16(aL[mf], bH[nf], acc[mf][nf], 0, 0, 0);
      }
    __syncthreads();
  }

  // ---- transition: stage B2 (W2 frag) + write relu(h) as bf16 A2 frags ----
  {
    const uint4* g2p = (const uint4*)W2F;
    uint4* d2 = (uint4*)&u.g2.B2[0][0][0];
#pragma unroll
    for (int s = 0; s < 8; ++s) { int f = tid + s * 256; d2[f] = g2p[f]; }
  }
#pragma unroll
  for (int mf = 0; mf < 4; ++mf)
#pragma unroll
    for (int nf = 0; nf < 4; ++nf) {
      int col = w * 64 + nf * 16 + l15;       // hidden index
      int kg = col >> 3, kin = col & 7;
#pragma unroll
      for (int j = 0; j < 4; ++j) {
        float vv = fmaxf(acc[mf][nf][j], 0.0f);
        u.g2.A2[kg][mf * 16 + l4 * 4 + j][kin] = bf16_rn(vv);
      }
    }
  __syncthreads();

  // ---- GEMM2: each wave computes rows [16w,16w+16) x 64 classes over full K=256 ----
  f32x4 acc2[4];
#pragma unroll
  for (int i = 0; i < 4; ++i) acc2[i] = zf;
#pragma unroll
  for (int ks = 0; ks < 8; ++ks) {
    short8 a2 = *(const short8*)&u.g2.A2[ks * 4 + l4][w * 16 + l15][0];
#pragma unroll
    for (int nf2 = 0; nf2 < 4; ++nf2) {
      short8 b2 = *(const short8*)&u.g2.B2[ks * 4 + l4][nf2 * 16 + l15][0];
      acc2[nf2] = __builtin_amdgcn_mfma_f32_16x16x32_bf16(a2, b2, acc2[nf2], 0, 0, 0);
    }
  }
#pragma unroll
  for (int nf2 = 0; nf2 < 4; ++nf2)
#pragma unroll
    for (int j = 0; j < 4; ++j) {
      int r = row0 + w * 16 + l4 * 4 + j;
      if (r < n) hout[(size_t)r * NCLS + nf2 * 16 + l15] = acc2[nf2][j];
    }
}

// ------------------------- SpMM (wave per row, lane = channel) -------------------------
__global__ void spmm_first(const int* __restrict__ rowptr, const int* __restrict__ colc,
                           const float* __restrict__ wcsr, const float* __restrict__ h,
                           float* __restrict__ tx1, float* __restrict__ acc,
                           const float* __restrict__ cw, int n) {
  int wid = (blockIdx.x * blockDim.x + threadIdx.x) >> 6;
  int lane = threadIdx.x & 63;
  if (wid >= n) return;
  int e0 = rowptr[wid], e1 = rowptr[wid + 1];
  float s = 0.0f;
  for (int e = e0; e < e1; ++e) {
    int c = colc[e];
    float wt = wcsr[e];
    s = fmaf(wt, h[(size_t)c * NCLS + lane], s);
  }
  size_t idx = (size_t)wid * NCLS + lane;
  tx1[idx] = s;
  acc[idx] = cw[0] * h[idx] + cw[1] * s;
}

__global__ void spmm_step(const int* __restrict__ rowptr, const int* __restrict__ colc,
                          const float* __restrict__ wcsr, const float* __restrict__ curb,
                          const float* __restrict__ prevb, float* __restrict__ nextb,
                          float* __restrict__ acc, const float* __restrict__ cw,
                          int k, int n) {
  int wid = (blockIdx.x * blockDim.x + threadIdx.x) >> 6;
  int lane = threadIdx.x & 63;
  if (wid >= n) return;
  int e0 = rowptr[wid], e1 = rowptr[wid + 1];
  float s = 0.0f;
  for (int e = e0; e < e1; ++e) {
    int c = colc[e];
    float wt = wcsr[e];
    s = fmaf(wt, curb[(size_t)c * NCLS + lane], s);
  }
  size_t idx = (size_t)wid * NCLS + lane;
  float t2 = 2.0f * s - prevb[idx];
  nextb[idx] = t2;
  acc[idx] += cw[k] * t2;
}

// ------------------------- log-softmax over 64 classes (in-place) -------------------------
__global__ void log_softmax_k(float* __restrict__ io, int n) {
  int wid = (blockIdx.x * blockDim.x + threadIdx.x) >> 6;
  int lane = threadIdx.x & 63;
  if (wid >= n) return;
  size_t idx = (size_t)wid * NCLS + lane;
  float v = io[idx];
  float m = v;
#pragma unroll
  for (int off = 32; off > 0; off >>= 1) m = fmaxf(m, __shfl_xor(m, off, 64));
  float ex = expf(v - m);
  float ssum = ex;
#pragma unroll
  for (int off = 32; off > 0; off >>= 1) ssum += __shfl_xor(ssum, off, 64);
  io[idx] = v - m - logf(ssum);
}

// ------------------------- launch -------------------------
extern "C" void kernel_launch(void* const* d_in, const int* in_sizes, int n_in,
                              void* d_out, int out_size, void* d_ws, size_t ws_size,
                              hipStream_t stream) {
  const float* x  = (const float*)d_in[0];
  const int*   ei = (const int*)d_in[1];
  const float* W1 = (const float*)d_in[2];
  const float* W2 = (const float*)d_in[3];
  const float* cw = (const float*)d_in[4];
  float* out = (float*)d_out;

  const int n = in_sizes[0] / NFEAT;     // 100000
  const int E = in_sizes[1] / 2;         // 1600000

  size_t off = 0;
  auto alloc = [&](size_t bytes) { size_t o = off; off += (bytes + 255) & ~(size_t)255; return o; };
  char* w = (char*)d_ws;
  size_t o_deg   = alloc((size_t)n * 4);
  size_t o_cnt   = alloc((size_t)n * 4);
  size_t o_cur   = alloc((size_t)n * 4);
  size_t o_dinv  = alloc((size_t)n * 4);
  size_t o_rp    = alloc((size_t)(n + 1) * 4);
  size_t o_bs    = alloc(4096 * 4);
  size_t o_w1fh  = alloc((size_t)KPAD * NHID * 2);
  size_t o_w1fl  = alloc((size_t)KPAD * NHID * 2);
  size_t o_w2f   = alloc((size_t)NHID * NCLS * 2);
  size_t o_colc  = alloc((size_t)E * 4);
  size_t o_wcsr  = alloc((size_t)E * 4);
  size_t o_bufH  = alloc((size_t)n * NCLS * 4);
  size_t o_bufA  = alloc((size_t)n * NCLS * 4);
  size_t o_bufB  = alloc((size_t)n * NCLS * 4);

  int*   deg    = (int*)(w + o_deg);
  int*   cnt    = (int*)(w + o_cnt);
  int*   curi   = (int*)(w + o_cur);
  float* dinv   = (float*)(w + o_dinv);
  int*   rowptr = (int*)(w + o_rp);
  int*   bsums  = (int*)(w + o_bs);
  unsigned short* W1Fh = (unsigned short*)(w + o_w1fh);
  unsigned short* W1Fl = (unsigned short*)(w + o_w1fl);
  unsigned short* W2F  = (unsigned short*)(w + o_w2f);
  int*   colc   = (int*)(w + o_colc);
  float* wcsr   = (float*)(w + o_wcsr);
  float* bufH   = (float*)(w + o_bufH);
  float* bufA   = (float*)(w + o_bufA);
  float* bufB   = (float*)(w + o_bufB);

  hipMemsetAsync(w + o_deg, 0, o_dinv - o_deg, stream);

  const int nb = (n + 255) / 256;

  conv_w1f<<<(KPAD * NHID + 255) / 256, 256, 0, stream>>>(W1, W1Fh, W1Fl);
  conv_w2f<<<(NHID * NCLS + 255) / 256, 256, 0, stream>>>(W2, W2F);

  edge_count<<<1024, 256, 0, stream>>>(ei, E, deg, cnt);
  make_dinv<<<nb, 256, 0, stream>>>(deg, dinv, n);
  scan_block<<<nb, 256, 0, stream>>>(cnt, rowptr, bsums, n);
  scan_sums<<<1, 1, 0, stream>>>(bsums, nb, rowptr);
  scan_add<<<nb, 256, 0, stream>>>(rowptr, bsums, n);
  scatter_edges<<<1024, 256, 0, stream>>>(ei, E, dinv, rowptr, curi, colc, wcsr);

  mlp_mfma<<<(n + 63) / 64, 256, 0, stream>>>(x, W1Fh, W1Fl, W2F, bufH, n);

  const int spmm_blocks = (n + 3) / 4;   // 4 waves per 256-thread block
  spmm_first<<<spmm_blocks, 256, 0, stream>>>(rowptr, colc, wcsr, bufH, bufA, out, cw, n);

  float* P = bufH;
  float* C = bufA;
  float* N = bufB;
  for (int k = 2; k <= KPOLY; ++k) {
    spmm_step<<<spmm_blocks, 256, 0, stream>>>(rowptr, colc, wcsr, C, P, N, out, cw, k, n);
    float* t = P; P = C; C = N; N = t;
  }

  log_softmax_k<<<spmm_blocks, 256, 0, stream>>>(out, n);
}

// Round 4
// 1205.390 us; speedup vs baseline: 2.4226x; 1.6270x over previous
//
#include <hip/hip_runtime.h>
#include <hip/hip_bf16.h>
#include <math.h>

#define NFEAT 500
#define KPAD  512
#define NHID  256
#define NCLS  64
#define KPOLY 10

typedef __attribute__((ext_vector_type(8))) short short8;
typedef __attribute__((ext_vector_type(4))) float f32x4;

__device__ inline unsigned short bf16_rn(float v) {
  unsigned u = __float_as_uint(v);
  return (unsigned short)((u + 0x7FFFu + ((u >> 16) & 1u)) >> 16);
}
__device__ inline void split2(float v, unsigned short& hi, unsigned short& lo) {
  unsigned short h = bf16_rn(v);
  float vh = __uint_as_float(((unsigned)h) << 16);
  lo = bf16_rn(v - vh);
  hi = h;
}

// ---------- weight pre-conversion into MFMA fragment layout ----------
__global__ void conv_w1f(const float* __restrict__ W1, unsigned short* __restrict__ Fh,
                         unsigned short* __restrict__ Fl) {
  int i = blockIdx.x * 256 + threadIdx.x;
  if (i >= KPAD * NHID) return;
  int kg = i >> 11, c = (i >> 3) & 255, kin = i & 7;
  int k = kg * 8 + kin;
  float v = (k < NFEAT) ? W1[c * NFEAT + k] : 0.0f;
  unsigned short h, l;
  split2(v, h, l);
  Fh[i] = h; Fl[i] = l;
}
__global__ void conv_w2f(const float* __restrict__ W2, unsigned short* __restrict__ F) {
  int i = blockIdx.x * 256 + threadIdx.x;
  if (i >= NHID * NCLS) return;
  int kg = i >> 9, c = (i >> 3) & 63, kin = i & 7;
  int k = kg * 8 + kin;
  F[i] = bf16_rn(W2[c * NHID + k]);
}

// ------------------------- CSR build -------------------------
__global__ void edge_count(const int* __restrict__ ei, int E,
                           int* __restrict__ deg, int* __restrict__ cnt) {
  int stride = gridDim.x * blockDim.x;
  for (int e = blockIdx.x * blockDim.x + threadIdx.x; e < E; e += stride) {
    int r = ei[e], c = ei[E + e];
    atomicAdd(&cnt[r], 1);
    if (r != c) atomicAdd(&deg[r], 1);
  }
}

__global__ void make_dinv(const int* __restrict__ deg, float* __restrict__ dinv, int n) {
  int i = blockIdx.x * blockDim.x + threadIdx.x;
  if (i < n) {
    int d = deg[i];
    dinv[i] = (d > 0) ? rsqrtf((float)d) : 0.0f;
  }
}

__global__ void scan_block(const int* __restrict__ cnt, int* __restrict__ rowptr,
                           int* __restrict__ bsums, int n) {
  __shared__ int s[256];
  int i = blockIdx.x * 256 + threadIdx.x;
  int v = (i < n) ? cnt[i] : 0;
  s[threadIdx.x] = v;
  __syncthreads();
  for (int off = 1; off < 256; off <<= 1) {
    int t = (threadIdx.x >= (unsigned)off) ? s[threadIdx.x - off] : 0;
    __syncthreads();
    s[threadIdx.x] += t;
    __syncthreads();
  }
  if (i < n) rowptr[i + 1] = s[threadIdx.x];
  if (threadIdx.x == 255) bsums[blockIdx.x] = s[255];
}

__global__ void scan_sums(int* __restrict__ bsums, int nb, int* __restrict__ rowptr) {
  if (threadIdx.x == 0 && blockIdx.x == 0) {
    int run = 0;
    for (int b = 0; b < nb; ++b) { int t = bsums[b]; bsums[b] = run; run += t; }
    rowptr[0] = 0;
  }
}

__global__ void scan_add(int* __restrict__ rowptr, const int* __restrict__ bsums, int n) {
  int i = blockIdx.x * 256 + threadIdx.x;
  if (i < n) rowptr[i + 1] += bsums[i >> 8];
}

// pack (col, weight) into int2 for one 8-B load per edge
__global__ void scatter_edges(const int* __restrict__ ei, int E,
                              const float* __restrict__ dinv,
                              const int* __restrict__ rowptr, int* __restrict__ cur,
                              int2* __restrict__ ecw) {
  int stride = gridDim.x * blockDim.x;
  for (int e = blockIdx.x * blockDim.x + threadIdx.x; e < E; e += stride) {
    int r = ei[e], c = ei[E + e];
    int pos = rowptr[r] + atomicAdd(&cur[r], 1);
    float wt = (r != c) ? (-dinv[r] * dinv[c]) : 0.0f;
    ecw[pos] = make_int2(c, __float_as_int(wt));
  }
}

// ------------------------- fused MLP via MFMA (bf16 hi/lo split) -------------------------
__global__ __launch_bounds__(256, 2) void mlp_mfma(
    const float* __restrict__ x, const unsigned short* __restrict__ W1Fh,
    const unsigned short* __restrict__ W1Fl, const unsigned short* __restrict__ W2F,
    float* __restrict__ hout, int n)
{
  __shared__ union {
    struct {
      unsigned short Ah[4][64][8], Al[4][64][8];
      unsigned short Bh[4][256][8], Bl[4][256][8];
    } g1;
    struct {
      unsigned short A2[32][64][8];
      unsigned short B2[32][64][8];
    } g2;
  } u;

  const int tid = threadIdx.x;
  const int w = tid >> 6;
  const int l = tid & 63;
  const int l15 = l & 15, l4 = l >> 4;
  const int row0 = blockIdx.x * 64;

  f32x4 acc[4][4];
  const f32x4 zf = {0.0f, 0.0f, 0.0f, 0.0f};
#pragma unroll
  for (int i = 0; i < 4; ++i)
#pragma unroll
    for (int j = 0; j < 4; ++j) acc[i][j] = zf;

  for (int t = 0; t < 16; ++t) {
    const int k0 = t * 32;
#pragma unroll
    for (int s = 0; s < 2; ++s) {
      int f = tid + s * 256;
      int r = f >> 3, slot = f & 7;
      int gr = row0 + r, gk = k0 + slot * 4;
      float4 v = make_float4(0.f, 0.f, 0.f, 0.f);
      if (gr < n && gk + 3 < NFEAT)
        v = *(const float4*)&x[(size_t)gr * NFEAT + gk];
      unsigned short a0, a1, a2, a3, b0, b1, b2, b3;
      split2(v.x, a0, b0); split2(v.y, a1, b1); split2(v.z, a2, b2); split2(v.w, a3, b3);
      int kg = slot >> 1, kin0 = (slot & 1) * 4;
      *(uint2*)&u.g1.Ah[kg][r][kin0] =
          make_uint2((unsigned)a0 | ((unsigned)a1 << 16), (unsigned)a2 | ((unsigned)a3 << 16));
      *(uint2*)&u.g1.Al[kg][r][kin0] =
          make_uint2((unsigned)b0 | ((unsigned)b1 << 16), (unsigned)b2 | ((unsigned)b3 << 16));
    }
    {
      const uint4* gh = (const uint4*)(W1Fh + (size_t)t * 8192);
      const uint4* gl = (const uint4*)(W1Fl + (size_t)t * 8192);
      uint4* dh = (uint4*)&u.g1.Bh[0][0][0];
      uint4* dl = (uint4*)&u.g1.Bl[0][0][0];
#pragma unroll
      for (int s = 0; s < 4; ++s) { int f = tid + s * 256; dh[f] = gh[f]; dl[f] = gl[f]; }
    }
    __syncthreads();

    short8 aH[4], aL[4], bH[4], bL[4];
#pragma unroll
    for (int mf = 0; mf < 4; ++mf) {
      aH[mf] = *(const short8*)&u.g1.Ah[l4][mf * 16 + l15][0];
      aL[mf] = *(const short8*)&u.g1.Al[l4][mf * 16 + l15][0];
    }
#pragma unroll
    for (int nf = 0; nf < 4; ++nf) {
      bH[nf] = *(const short8*)&u.g1.Bh[l4][w * 64 + nf * 16 + l15][0];
      bL[nf] = *(const short8*)&u.g1.Bl[l4][w * 64 + nf * 16 + l15][0];
    }
#pragma unroll
    for (int mf = 0; mf < 4; ++mf)
#pragma unroll
      for (int nf = 0; nf < 4; ++nf) {
        acc[mf][nf] = __builtin_amdgcn_mfma_f32_16x16x32_bf16(aH[mf], bH[nf], acc[mf][nf], 0, 0, 0);
        acc[mf][nf] = __builtin_amdgcn_mfma_f32_16x16x32_bf16(aH[mf], bL[nf], acc[mf][nf], 0, 0, 0);
        acc[mf][nf] = __builtin_amdgcn_mfma_f32_16x16x32_bf16(aL[mf], bH[nf], acc[mf][nf], 0, 0, 0);
      }
    __syncthreads();
  }

  {
    const uint4* g2p = (const uint4*)W2F;
    uint4* d2 = (uint4*)&u.g2.B2[0][0][0];
#pragma unroll
    for (int s = 0; s < 8; ++s) { int f = tid + s * 256; d2[f] = g2p[f]; }
  }
#pragma unroll
  for (int mf = 0; mf < 4; ++mf)
#pragma unroll
    for (int nf = 0; nf < 4; ++nf) {
      int col = w * 64 + nf * 16 + l15;
      int kg = col >> 3, kin = col & 7;
#pragma unroll
      for (int j = 0; j < 4; ++j) {
        float vv = fmaxf(acc[mf][nf][j], 0.0f);
        u.g2.A2[kg][mf * 16 + l4 * 4 + j][kin] = bf16_rn(vv);
      }
    }
  __syncthreads();

  f32x4 acc2[4];
#pragma unroll
  for (int i = 0; i < 4; ++i) acc2[i] = zf;
#pragma unroll
  for (int ks = 0; ks < 8; ++ks) {
    short8 a2 = *(const short8*)&u.g2.A2[ks * 4 + l4][w * 16 + l15][0];
#pragma unroll
    for (int nf2 = 0; nf2 < 4; ++nf2) {
      short8 b2 = *(const short8*)&u.g2.B2[ks * 4 + l4][nf2 * 16 + l15][0];
      acc2[nf2] = __builtin_amdgcn_mfma_f32_16x16x32_bf16(a2, b2, acc2[nf2], 0, 0, 0);
    }
  }
#pragma unroll
  for (int nf2 = 0; nf2 < 4; ++nf2)
#pragma unroll
    for (int j = 0; j < 4; ++j) {
      int r = row0 + w * 16 + l4 * 4 + j;
      if (r < n) hout[(size_t)r * NCLS + nf2 * 16 + l15] = acc2[nf2][j];
    }
}

// ------------------------- SpMM (wave per row, lane = channel, 8-deep MLP) -------------------------
__device__ inline float gather_row_sum(const int* __restrict__ rowptr,
                                       const int2* __restrict__ ecw,
                                       const float* __restrict__ src,
                                       int wid, int lane) {
  int e0 = rowptr[wid], e1 = rowptr[wid + 1];
  float s = 0.0f;
  for (int e = e0; e < e1; e += 8) {
    int cc[8]; float ww[8];
#pragma unroll
    for (int j = 0; j < 8; ++j) {
      int ee = e + j;
      int eclamp = (ee < e1) ? ee : (e1 - 1);   // always-valid load
      int2 t = ecw[eclamp];
      cc[j] = t.x;
      ww[j] = (ee < e1) ? __int_as_float(t.y) : 0.0f;  // zero pad-weights
    }
    float hv[8];
#pragma unroll
    for (int j = 0; j < 8; ++j) hv[j] = src[(size_t)cc[j] * NCLS + lane];
#pragma unroll
    for (int j = 0; j < 8; ++j) s = fmaf(ww[j], hv[j], s);
  }
  return s;
}

__global__ void spmm_first(const int* __restrict__ rowptr, const int2* __restrict__ ecw,
                           const float* __restrict__ h, float* __restrict__ tx1,
                           float* __restrict__ acc, const float* __restrict__ cw, int n) {
  int wid = (blockIdx.x * blockDim.x + threadIdx.x) >> 6;
  int lane = threadIdx.x & 63;
  if (wid >= n) return;
  float s = gather_row_sum(rowptr, ecw, h, wid, lane);
  size_t idx = (size_t)wid * NCLS + lane;
  tx1[idx] = s;
  acc[idx] = cw[0] * h[idx] + cw[1] * s;
}

__global__ void spmm_step(const int* __restrict__ rowptr, const int2* __restrict__ ecw,
                          const float* __restrict__ curb, const float* __restrict__ prevb,
                          float* __restrict__ nextb, float* __restrict__ acc,
                          const float* __restrict__ cw, int k, int last, int n) {
  int wid = (blockIdx.x * blockDim.x + threadIdx.x) >> 6;
  int lane = threadIdx.x & 63;
  if (wid >= n) return;
  float s = gather_row_sum(rowptr, ecw, curb, wid, lane);
  size_t idx = (size_t)wid * NCLS + lane;
  float t2 = 2.0f * s - prevb[idx];
  if (!last) {
    nextb[idx] = t2;
    acc[idx] += cw[k] * t2;
  } else {
    // final pass: finish accumulation and apply log-softmax in-register
    float v = acc[idx] + cw[k] * t2;
    float m = v;
#pragma unroll
    for (int off = 32; off > 0; off >>= 1) m = fmaxf(m, __shfl_xor(m, off, 64));
    float ex = expf(v - m);
    float ssum = ex;
#pragma unroll
    for (int off = 32; off > 0; off >>= 1) ssum += __shfl_xor(ssum, off, 64);
    acc[idx] = v - m - logf(ssum);
  }
}

// ------------------------- launch -------------------------
extern "C" void kernel_launch(void* const* d_in, const int* in_sizes, int n_in,
                              void* d_out, int out_size, void* d_ws, size_t ws_size,
                              hipStream_t stream) {
  const float* x  = (const float*)d_in[0];
  const int*   ei = (const int*)d_in[1];
  const float* W1 = (const float*)d_in[2];
  const float* W2 = (const float*)d_in[3];
  const float* cw = (const float*)d_in[4];
  float* out = (float*)d_out;

  const int n = in_sizes[0] / NFEAT;     // 100000
  const int E = in_sizes[1] / 2;         // 1600000

  size_t off = 0;
  auto alloc = [&](size_t bytes) { size_t o = off; off += (bytes + 255) & ~(size_t)255; return o; };
  char* w = (char*)d_ws;
  size_t o_deg   = alloc((size_t)n * 4);
  size_t o_cnt   = alloc((size_t)n * 4);
  size_t o_cur   = alloc((size_t)n * 4);
  size_t o_dinv  = alloc((size_t)n * 4);
  size_t o_rp    = alloc((size_t)(n + 1) * 4);
  size_t o_bs    = alloc(4096 * 4);
  size_t o_w1fh  = alloc((size_t)KPAD * NHID * 2);
  size_t o_w1fl  = alloc((size_t)KPAD * NHID * 2);
  size_t o_w2f   = alloc((size_t)NHID * NCLS * 2);
  size_t o_ecw   = alloc((size_t)E * 8);
  size_t o_bufH  = alloc((size_t)n * NCLS * 4);
  size_t o_bufA  = alloc((size_t)n * NCLS * 4);
  size_t o_bufB  = alloc((size_t)n * NCLS * 4);

  int*   deg    = (int*)(w + o_deg);
  int*   cnt    = (int*)(w + o_cnt);
  int*   curi   = (int*)(w + o_cur);
  float* dinv   = (float*)(w + o_dinv);
  int*   rowptr = (int*)(w + o_rp);
  int*   bsums  = (int*)(w + o_bs);
  unsigned short* W1Fh = (unsigned short*)(w + o_w1fh);
  unsigned short* W1Fl = (unsigned short*)(w + o_w1fl);
  unsigned short* W2F  = (unsigned short*)(w + o_w2f);
  int2*  ecw    = (int2*)(w + o_ecw);
  float* bufH   = (float*)(w + o_bufH);
  float* bufA   = (float*)(w + o_bufA);
  float* bufB   = (float*)(w + o_bufB);

  hipMemsetAsync(w + o_deg, 0, o_dinv - o_deg, stream);

  const int nb = (n + 255) / 256;

  conv_w1f<<<(KPAD * NHID + 255) / 256, 256, 0, stream>>>(W1, W1Fh, W1Fl);
  conv_w2f<<<(NHID * NCLS + 255) / 256, 256, 0, stream>>>(W2, W2F);

  edge_count<<<1024, 256, 0, stream>>>(ei, E, deg, cnt);
  make_dinv<<<nb, 256, 0, stream>>>(deg, dinv, n);
  scan_block<<<nb, 256, 0, stream>>>(cnt, rowptr, bsums, n);
  scan_sums<<<1, 1, 0, stream>>>(bsums, nb, rowptr);
  scan_add<<<nb, 256, 0, stream>>>(rowptr, bsums, n);
  scatter_edges<<<1024, 256, 0, stream>>>(ei, E, dinv, rowptr, curi, ecw);

  mlp_mfma<<<(n + 63) / 64, 256, 0, stream>>>(x, W1Fh, W1Fl, W2F, bufH, n);

  const int spmm_blocks = (n + 3) / 4;   // 4 waves per 256-thread block
  spmm_first<<<spmm_blocks, 256, 0, stream>>>(rowptr, ecw, bufH, bufA, out, cw, n);

  float* P = bufH;
  float* C = bufA;
  float* N = bufB;
  for (int k = 2; k <= KPOLY; ++k) {
    spmm_step<<<spmm_blocks, 256, 0, stream>>>(rowptr, ecw, C, P, N, out, cw, k,
                                               (k == KPOLY) ? 1 : 0, n);
    float* t = P; P = C; C = N; N = t;
  }
}

// Round 5
// 1141.704 us; speedup vs baseline: 2.5578x; 1.0558x over previous
//
#include <hip/hip_runtime.h>
#include <hip/hip_bf16.h>
#include <math.h>

#define NFEAT 500
#define KPAD  512
#define NHID  256
#define NCLS  64
#define KPOLY 10

typedef __attribute__((ext_vector_type(8))) short short8;
typedef __attribute__((ext_vector_type(4))) float f32x4;

__device__ inline unsigned short bf16_rn(float v) {
  unsigned u = __float_as_uint(v);
  return (unsigned short)((u + 0x7FFFu + ((u >> 16) & 1u)) >> 16);
}
__device__ inline float bf16_tof(unsigned short u) {
  return __uint_as_float(((unsigned)u) << 16);
}
__device__ inline void split2(float v, unsigned short& hi, unsigned short& lo) {
  unsigned short h = bf16_rn(v);
  float vh = __uint_as_float(((unsigned)h) << 16);
  lo = bf16_rn(v - vh);
  hi = h;
}

// ---------- weight pre-conversion into MFMA fragment layout ----------
__global__ void conv_w1f(const float* __restrict__ W1, unsigned short* __restrict__ Fh,
                         unsigned short* __restrict__ Fl) {
  int i = blockIdx.x * 256 + threadIdx.x;
  if (i >= KPAD * NHID) return;
  int kg = i >> 11, c = (i >> 3) & 255, kin = i & 7;
  int k = kg * 8 + kin;
  float v = (k < NFEAT) ? W1[c * NFEAT + k] : 0.0f;
  unsigned short h, l;
  split2(v, h, l);
  Fh[i] = h; Fl[i] = l;
}
__global__ void conv_w2f(const float* __restrict__ W2, unsigned short* __restrict__ F) {
  int i = blockIdx.x * 256 + threadIdx.x;
  if (i >= NHID * NCLS) return;
  int kg = i >> 9, c = (i >> 3) & 63, kin = i & 7;
  int k = kg * 8 + kin;
  F[i] = bf16_rn(W2[c * NHID + k]);
}

// ------------------------- CSR build -------------------------
__global__ void edge_count(const int* __restrict__ ei, int E,
                           int* __restrict__ deg, int* __restrict__ cnt) {
  int stride = gridDim.x * blockDim.x;
  for (int e = blockIdx.x * blockDim.x + threadIdx.x; e < E; e += stride) {
    int r = ei[e], c = ei[E + e];
    atomicAdd(&cnt[r], 1);
    if (r != c) atomicAdd(&deg[r], 1);
  }
}

__global__ void make_dinv(const int* __restrict__ deg, float* __restrict__ dinv, int n) {
  int i = blockIdx.x * blockDim.x + threadIdx.x;
  if (i < n) {
    int d = deg[i];
    dinv[i] = (d > 0) ? rsqrtf((float)d) : 0.0f;
  }
}

__global__ void scan_block(const int* __restrict__ cnt, int* __restrict__ rowptr,
                           int* __restrict__ bsums, int n) {
  __shared__ int s[256];
  int i = blockIdx.x * 256 + threadIdx.x;
  int v = (i < n) ? cnt[i] : 0;
  s[threadIdx.x] = v;
  __syncthreads();
  for (int off = 1; off < 256; off <<= 1) {
    int t = (threadIdx.x >= (unsigned)off) ? s[threadIdx.x - off] : 0;
    __syncthreads();
    s[threadIdx.x] += t;
    __syncthreads();
  }
  if (i < n) rowptr[i + 1] = s[threadIdx.x];
  if (threadIdx.x == 255) bsums[blockIdx.x] = s[255];
}

__global__ void scan_sums(int* __restrict__ bsums, int nb, int* __restrict__ rowptr) {
  if (threadIdx.x == 0 && blockIdx.x == 0) {
    int run = 0;
    for (int b = 0; b < nb; ++b) { int t = bsums[b]; bsums[b] = run; run += t; }
    rowptr[0] = 0;
  }
}

__global__ void scan_add(int* __restrict__ rowptr, const int* __restrict__ bsums, int n) {
  int i = blockIdx.x * 256 + threadIdx.x;
  if (i < n) rowptr[i + 1] += bsums[i >> 8];
}

__global__ void scatter_edges(const int* __restrict__ ei, int E,
                              const float* __restrict__ dinv,
                              const int* __restrict__ rowptr, int* __restrict__ cur,
                              int2* __restrict__ ecw) {
  int stride = gridDim.x * blockDim.x;
  for (int e = blockIdx.x * blockDim.x + threadIdx.x; e < E; e += stride) {
    int r = ei[e], c = ei[E + e];
    int pos = rowptr[r] + atomicAdd(&cur[r], 1);
    float wt = (r != c) ? (-dinv[r] * dinv[c]) : 0.0f;
    ecw[pos] = make_int2(c, __float_as_int(wt));
  }
}

// ------------------------- fused MLP via MFMA (bf16 hi/lo split) -------------------------
// LDS only for A exchange; B fragments read直接 from global (L2-resident, coalesced).
__global__ __launch_bounds__(256, 3) void mlp_mfma(
    const float* __restrict__ x, const unsigned short* __restrict__ W1Fh,
    const unsigned short* __restrict__ W1Fl, const unsigned short* __restrict__ W2F,
    unsigned short* __restrict__ hout, int n)
{
  __shared__ union {
    struct { unsigned short Ah[4][64][8], Al[4][64][8]; } g1;   // 8 KB
    struct { unsigned short A2[32][64][8]; } g2;                // 32 KB
  } u;

  const int tid = threadIdx.x;
  const int w = tid >> 6;
  const int l = tid & 63;
  const int l15 = l & 15, l4 = l >> 4;
  const int row0 = blockIdx.x * 64;

  f32x4 acc[4][4];
  const f32x4 zf = {0.0f, 0.0f, 0.0f, 0.0f};
#pragma unroll
  for (int i = 0; i < 4; ++i)
#pragma unroll
    for (int j = 0; j < 4; ++j) acc[i][j] = zf;

  for (int t = 0; t < 16; ++t) {
    const int k0 = t * 32;
    // issue B-fragment global loads first (latency hides under A staging + barrier)
    short8 bH[4], bL[4];
#pragma unroll
    for (int nf = 0; nf < 4; ++nf) {
      size_t bi = (size_t)t * 8192 + ((size_t)l4 * 256 + w * 64 + nf * 16 + l15) * 8;
      bH[nf] = *(const short8*)(W1Fh + bi);
      bL[nf] = *(const short8*)(W1Fl + bi);
    }
    // stage A: x[row0..+64][k0..+32) fp32 -> split bf16 hi/lo into [4][64][8]
#pragma unroll
    for (int s = 0; s < 2; ++s) {
      int f = tid + s * 256;
      int r = f >> 3, slot = f & 7;
      int gr = row0 + r, gk = k0 + slot * 4;
      float4 v = make_float4(0.f, 0.f, 0.f, 0.f);
      if (gr < n && gk + 3 < NFEAT)
        v = *(const float4*)&x[(size_t)gr * NFEAT + gk];
      unsigned short a0, a1, a2, a3, b0, b1, b2, b3;
      split2(v.x, a0, b0); split2(v.y, a1, b1); split2(v.z, a2, b2); split2(v.w, a3, b3);
      int kg = slot >> 1, kin0 = (slot & 1) * 4;
      *(uint2*)&u.g1.Ah[kg][r][kin0] =
          make_uint2((unsigned)a0 | ((unsigned)a1 << 16), (unsigned)a2 | ((unsigned)a3 << 16));
      *(uint2*)&u.g1.Al[kg][r][kin0] =
          make_uint2((unsigned)b0 | ((unsigned)b1 << 16), (unsigned)b2 | ((unsigned)b3 << 16));
    }
    __syncthreads();

#pragma unroll
    for (int mf = 0; mf < 4; ++mf) {
      short8 aH = *(const short8*)&u.g1.Ah[l4][mf * 16 + l15][0];
      short8 aL = *(const short8*)&u.g1.Al[l4][mf * 16 + l15][0];
#pragma unroll
      for (int nf = 0; nf < 4; ++nf) {
        acc[mf][nf] = __builtin_amdgcn_mfma_f32_16x16x32_bf16(aH, bH[nf], acc[mf][nf], 0, 0, 0);
        acc[mf][nf] = __builtin_amdgcn_mfma_f32_16x16x32_bf16(aH, bL[nf], acc[mf][nf], 0, 0, 0);
        acc[mf][nf] = __builtin_amdgcn_mfma_f32_16x16x32_bf16(aL, bH[nf], acc[mf][nf], 0, 0, 0);
      }
    }
    __syncthreads();
  }

  // ---- exchange relu(h) as bf16 A2 frags ----
#pragma unroll
  for (int mf = 0; mf < 4; ++mf)
#pragma unroll
    for (int nf = 0; nf < 4; ++nf) {
      int col = w * 64 + nf * 16 + l15;
      int kg = col >> 3, kin = col & 7;
#pragma unroll
      for (int j = 0; j < 4; ++j) {
        float vv = fmaxf(acc[mf][nf][j], 0.0f);
        u.g2.A2[kg][mf * 16 + l4 * 4 + j][kin] = bf16_rn(vv);
      }
    }
  __syncthreads();

  // ---- GEMM2: rows [16w,16w+16) x 64 classes, B2 direct from global ----
  f32x4 acc2[4];
#pragma unroll
  for (int i = 0; i < 4; ++i) acc2[i] = zf;
#pragma unroll
  for (int ks = 0; ks < 8; ++ks) {
    short8 a2 = *(const short8*)&u.g2.A2[ks * 4 + l4][w * 16 + l15][0];
#pragma unroll
    for (int nf2 = 0; nf2 < 4; ++nf2) {
      size_t bi = ((size_t)(ks * 4 + l4) * 64 + nf2 * 16 + l15) * 8;
      short8 b2 = *(const short8*)(W2F + bi);
      acc2[nf2] = __builtin_amdgcn_mfma_f32_16x16x32_bf16(a2, b2, acc2[nf2], 0, 0, 0);
    }
  }
#pragma unroll
  for (int nf2 = 0; nf2 < 4; ++nf2)
#pragma unroll
    for (int j = 0; j < 4; ++j) {
      int r = row0 + w * 16 + l4 * 4 + j;
      if (r < n) hout[(size_t)r * NCLS + nf2 * 16 + l15] = bf16_rn(acc2[nf2][j]);
    }
}

// ------------------------- SpMM (wave per row, lane = channel, 8-deep MLP, bf16 src) ---------
__device__ inline float gather_row_sum(const int* __restrict__ rowptr,
                                       const int2* __restrict__ ecw,
                                       const unsigned short* __restrict__ src,
                                       int wid, int lane) {
  int e0 = rowptr[wid], e1 = rowptr[wid + 1];
  float s = 0.0f;
  for (int e = e0; e < e1; e += 8) {
    int cc[8]; float ww[8];
#pragma unroll
    for (int j = 0; j < 8; ++j) {
      int ee = e + j;
      int eclamp = (ee < e1) ? ee : (e1 - 1);
      int2 t = ecw[eclamp];
      cc[j] = t.x;
      ww[j] = (ee < e1) ? __int_as_float(t.y) : 0.0f;
    }
    unsigned short hv[8];
#pragma unroll
    for (int j = 0; j < 8; ++j) hv[j] = src[(size_t)cc[j] * NCLS + lane];
#pragma unroll
    for (int j = 0; j < 8; ++j) s = fmaf(ww[j], bf16_tof(hv[j]), s);
  }
  return s;
}

__global__ void spmm_first(const int* __restrict__ rowptr, const int2* __restrict__ ecw,
                           const unsigned short* __restrict__ h, unsigned short* __restrict__ tx1,
                           float* __restrict__ acc, const float* __restrict__ cw, int n) {
  int wid = (blockIdx.x * blockDim.x + threadIdx.x) >> 6;
  int lane = threadIdx.x & 63;
  if (wid >= n) return;
  float s = gather_row_sum(rowptr, ecw, h, wid, lane);
  size_t idx = (size_t)wid * NCLS + lane;
  tx1[idx] = bf16_rn(s);
  acc[idx] = cw[0] * bf16_tof(h[idx]) + cw[1] * s;
}

__global__ void spmm_step(const int* __restrict__ rowptr, const int2* __restrict__ ecw,
                          const unsigned short* __restrict__ curb,
                          const unsigned short* __restrict__ prevb,
                          unsigned short* __restrict__ nextb, float* __restrict__ acc,
                          const float* __restrict__ cw, int k, int last, int n) {
  int wid = (blockIdx.x * blockDim.x + threadIdx.x) >> 6;
  int lane = threadIdx.x & 63;
  if (wid >= n) return;
  float s = gather_row_sum(rowptr, ecw, curb, wid, lane);
  size_t idx = (size_t)wid * NCLS + lane;
  float t2 = 2.0f * s - bf16_tof(prevb[idx]);
  if (!last) {
    nextb[idx] = bf16_rn(t2);
    acc[idx] += cw[k] * t2;
  } else {
    float v = acc[idx] + cw[k] * t2;
    float m = v;
#pragma unroll
    for (int off = 32; off > 0; off >>= 1) m = fmaxf(m, __shfl_xor(m, off, 64));
    float ex = expf(v - m);
    float ssum = ex;
#pragma unroll
    for (int off = 32; off > 0; off >>= 1) ssum += __shfl_xor(ssum, off, 64);
    acc[idx] = v - m - logf(ssum);
  }
}

// ------------------------- launch -------------------------
extern "C" void kernel_launch(void* const* d_in, const int* in_sizes, int n_in,
                              void* d_out, int out_size, void* d_ws, size_t ws_size,
                              hipStream_t stream) {
  const float* x  = (const float*)d_in[0];
  const int*   ei = (const int*)d_in[1];
  const float* W1 = (const float*)d_in[2];
  const float* W2 = (const float*)d_in[3];
  const float* cw = (const float*)d_in[4];
  float* out = (float*)d_out;

  const int n = in_sizes[0] / NFEAT;     // 100000
  const int E = in_sizes[1] / 2;         // 1600000

  size_t off = 0;
  auto alloc = [&](size_t bytes) { size_t o = off; off += (bytes + 255) & ~(size_t)255; return o; };
  char* w = (char*)d_ws;
  size_t o_deg   = alloc((size_t)n * 4);
  size_t o_cnt   = alloc((size_t)n * 4);
  size_t o_cur   = alloc((size_t)n * 4);
  size_t o_dinv  = alloc((size_t)n * 4);
  size_t o_rp    = alloc((size_t)(n + 1) * 4);
  size_t o_bs    = alloc(4096 * 4);
  size_t o_w1fh  = alloc((size_t)KPAD * NHID * 2);
  size_t o_w1fl  = alloc((size_t)KPAD * NHID * 2);
  size_t o_w2f   = alloc((size_t)NHID * NCLS * 2);
  size_t o_ecw   = alloc((size_t)E * 8);
  size_t o_bufH  = alloc((size_t)n * NCLS * 2);
  size_t o_bufA  = alloc((size_t)n * NCLS * 2);
  size_t o_bufB  = alloc((size_t)n * NCLS * 2);

  int*   deg    = (int*)(w + o_deg);
  int*   cnt    = (int*)(w + o_cnt);
  int*   curi   = (int*)(w + o_cur);
  float* dinv   = (float*)(w + o_dinv);
  int*   rowptr = (int*)(w + o_rp);
  int*   bsums  = (int*)(w + o_bs);
  unsigned short* W1Fh = (unsigned short*)(w + o_w1fh);
  unsigned short* W1Fl = (unsigned short*)(w + o_w1fl);
  unsigned short* W2F  = (unsigned short*)(w + o_w2f);
  int2*  ecw    = (int2*)(w + o_ecw);
  unsigned short* bufH = (unsigned short*)(w + o_bufH);
  unsigned short* bufA = (unsigned short*)(w + o_bufA);
  unsigned short* bufB = (unsigned short*)(w + o_bufB);

  hipMemsetAsync(w + o_deg, 0, o_dinv - o_deg, stream);

  const int nb = (n + 255) / 256;

  conv_w1f<<<(KPAD * NHID + 255) / 256, 256, 0, stream>>>(W1, W1Fh, W1Fl);
  conv_w2f<<<(NHID * NCLS + 255) / 256, 256, 0, stream>>>(W2, W2F);

  edge_count<<<1024, 256, 0, stream>>>(ei, E, deg, cnt);
  make_dinv<<<nb, 256, 0, stream>>>(deg, dinv, n);
  scan_block<<<nb, 256, 0, stream>>>(cnt, rowptr, bsums, n);
  scan_sums<<<1, 1, 0, stream>>>(bsums, nb, rowptr);
  scan_add<<<nb, 256, 0, stream>>>(rowptr, bsums, n);
  scatter_edges<<<1024, 256, 0, stream>>>(ei, E, dinv, rowptr, curi, ecw);

  mlp_mfma<<<(n + 63) / 64, 256, 0, stream>>>(x, W1Fh, W1Fl, W2F, bufH, n);

  const int spmm_blocks = (n + 3) / 4;   // 4 waves per 256-thread block
  spmm_first<<<spmm_blocks, 256, 0, stream>>>(rowptr, ecw, bufH, bufA, out, cw, n);

  unsigned short* P = bufH;
  unsigned short* C = bufA;
  unsigned short* N = bufB;
  for (int k = 2; k <= KPOLY; ++k) {
    spmm_step<<<spmm_blocks, 256, 0, stream>>>(rowptr, ecw, C, P, N, out, cw, k,
                                               (k == KPOLY) ? 1 : 0, n);
    unsigned short* t = P; P = C; C = N; N = t;
  }
}

// Round 6
// 821.683 us; speedup vs baseline: 3.5539x; 1.3895x over previous
//
#include <hip/hip_runtime.h>
#include <hip/hip_bf16.h>
#include <math.h>

#define NFEAT 500
#define KPAD  512
#define NHID  256
#define NCLS  64
#define KPOLY 10

typedef __attribute__((ext_vector_type(8))) short short8;
typedef __attribute__((ext_vector_type(4))) float f32x4;

__device__ inline unsigned short bf16_rn(float v) {
  unsigned u = __float_as_uint(v);
  return (unsigned short)((u + 0x7FFFu + ((u >> 16) & 1u)) >> 16);
}
__device__ inline float bf16_tof(unsigned short u) {
  return __uint_as_float(((unsigned)u) << 16);
}
__device__ inline float u2f_lo(unsigned u) { return __uint_as_float(u << 16); }
__device__ inline float u2f_hi(unsigned u) { return __uint_as_float(u & 0xFFFF0000u); }
__device__ inline unsigned pack2(float a, float b) {
  return (unsigned)bf16_rn(a) | ((unsigned)bf16_rn(b) << 16);
}
__device__ inline void split2(float v, unsigned short& hi, unsigned short& lo) {
  unsigned short h = bf16_rn(v);
  float vh = __uint_as_float(((unsigned)h) << 16);
  lo = bf16_rn(v - vh);
  hi = h;
}

// ---------- weight pre-conversion into MFMA fragment layout ----------
__global__ void conv_w1f(const float* __restrict__ W1, unsigned short* __restrict__ Fh,
                         unsigned short* __restrict__ Fl) {
  int i = blockIdx.x * 256 + threadIdx.x;
  if (i >= KPAD * NHID) return;
  int kg = i >> 11, c = (i >> 3) & 255, kin = i & 7;
  int k = kg * 8 + kin;
  float v = (k < NFEAT) ? W1[c * NFEAT + k] : 0.0f;
  unsigned short h, l;
  split2(v, h, l);
  Fh[i] = h; Fl[i] = l;
}
__global__ void conv_w2f(const float* __restrict__ W2, unsigned short* __restrict__ F) {
  int i = blockIdx.x * 256 + threadIdx.x;
  if (i >= NHID * NCLS) return;
  int kg = i >> 9, c = (i >> 3) & 63, kin = i & 7;
  int k = kg * 8 + kin;
  F[i] = bf16_rn(W2[c * NHID + k]);
}

// ------------------------- CSR build -------------------------
__global__ void edge_count(const int* __restrict__ ei, int E,
                           int* __restrict__ deg, int* __restrict__ cnt) {
  int stride = gridDim.x * blockDim.x;
  for (int e = blockIdx.x * blockDim.x + threadIdx.x; e < E; e += stride) {
    int r = ei[e], c = ei[E + e];
    atomicAdd(&cnt[r], 1);
    if (r != c) atomicAdd(&deg[r], 1);
  }
}

__global__ void make_dinv(const int* __restrict__ deg, float* __restrict__ dinv, int n) {
  int i = blockIdx.x * blockDim.x + threadIdx.x;
  if (i < n) {
    int d = deg[i];
    dinv[i] = (d > 0) ? rsqrtf((float)d) : 0.0f;
  }
}

__global__ void scan_block(const int* __restrict__ cnt, int* __restrict__ rowptr,
                           int* __restrict__ bsums, int n) {
  __shared__ int s[256];
  int i = blockIdx.x * 256 + threadIdx.x;
  int v = (i < n) ? cnt[i] : 0;
  s[threadIdx.x] = v;
  __syncthreads();
  for (int off = 1; off < 256; off <<= 1) {
    int t = (threadIdx.x >= (unsigned)off) ? s[threadIdx.x - off] : 0;
    __syncthreads();
    s[threadIdx.x] += t;
    __syncthreads();
  }
  if (i < n) rowptr[i + 1] = s[threadIdx.x];
  if (threadIdx.x == 255) bsums[blockIdx.x] = s[255];
}

__global__ void scan_sums(int* __restrict__ bsums, int nb, int* __restrict__ rowptr) {
  if (threadIdx.x == 0 && blockIdx.x == 0) {
    int run = 0;
    for (int b = 0; b < nb; ++b) { int t = bsums[b]; bsums[b] = run; run += t; }
    rowptr[0] = 0;
  }
}

__global__ void scan_add(int* __restrict__ rowptr, const int* __restrict__ bsums, int n) {
  int i = blockIdx.x * 256 + threadIdx.x;
  if (i < n) rowptr[i + 1] += bsums[i >> 8];
}

__global__ void scatter_edges(const int* __restrict__ ei, int E,
                              const float* __restrict__ dinv,
                              const int* __restrict__ rowptr, int* __restrict__ cur,
                              int2* __restrict__ ecw) {
  int stride = gridDim.x * blockDim.x;
  for (int e = blockIdx.x * blockDim.x + threadIdx.x; e < E; e += stride) {
    int r = ei[e], c = ei[E + e];
    int pos = rowptr[r] + atomicAdd(&cur[r], 1);
    float wt = (r != c) ? (-dinv[r] * dinv[c]) : 0.0f;
    ecw[pos] = make_int2(c, __float_as_int(wt));
  }
}

// ------------------------- fused MLP via MFMA (bf16 hi/lo split) -------------------------
__global__ __launch_bounds__(256, 4) void mlp_mfma(
    const float* __restrict__ x, const unsigned short* __restrict__ W1Fh,
    const unsigned short* __restrict__ W1Fl, const unsigned short* __restrict__ W2F,
    unsigned short* __restrict__ hout, int n)
{
  __shared__ union {
    struct { unsigned short Ah[4][64][8], Al[4][64][8]; } g1;   // 8 KB
    struct { unsigned short A2[32][64][8]; } g2;                // 32 KB
  } u;

  const int tid = threadIdx.x;
  const int w = tid >> 6;
  const int l = tid & 63;
  const int l15 = l & 15, l4 = l >> 4;
  const int row0 = blockIdx.x * 64;

  f32x4 acc[4][4];
  const f32x4 zf = {0.0f, 0.0f, 0.0f, 0.0f};
#pragma unroll
  for (int i = 0; i < 4; ++i)
#pragma unroll
    for (int j = 0; j < 4; ++j) acc[i][j] = zf;

  for (int t = 0; t < 16; ++t) {
    const int k0 = t * 32;
    short8 bH[4], bL[4];
#pragma unroll
    for (int nf = 0; nf < 4; ++nf) {
      size_t bi = (size_t)t * 8192 + ((size_t)l4 * 256 + w * 64 + nf * 16 + l15) * 8;
      bH[nf] = *(const short8*)(W1Fh + bi);
      bL[nf] = *(const short8*)(W1Fl + bi);
    }
#pragma unroll
    for (int s = 0; s < 2; ++s) {
      int f = tid + s * 256;
      int r = f >> 3, slot = f & 7;
      int gr = row0 + r, gk = k0 + slot * 4;
      float4 v = make_float4(0.f, 0.f, 0.f, 0.f);
      if (gr < n && gk + 3 < NFEAT)
        v = *(const float4*)&x[(size_t)gr * NFEAT + gk];
      unsigned short a0, a1, a2, a3, b0, b1, b2, b3;
      split2(v.x, a0, b0); split2(v.y, a1, b1); split2(v.z, a2, b2); split2(v.w, a3, b3);
      int kg = slot >> 1, kin0 = (slot & 1) * 4;
      *(uint2*)&u.g1.Ah[kg][r][kin0] =
          make_uint2((unsigned)a0 | ((unsigned)a1 << 16), (unsigned)a2 | ((unsigned)a3 << 16));
      *(uint2*)&u.g1.Al[kg][r][kin0] =
          make_uint2((unsigned)b0 | ((unsigned)b1 << 16), (unsigned)b2 | ((unsigned)b3 << 16));
    }
    __syncthreads();

#pragma unroll
    for (int mf = 0; mf < 4; ++mf) {
      short8 aH = *(const short8*)&u.g1.Ah[l4][mf * 16 + l15][0];
      short8 aL = *(const short8*)&u.g1.Al[l4][mf * 16 + l15][0];
#pragma unroll
      for (int nf = 0; nf < 4; ++nf) {
        acc[mf][nf] = __builtin_amdgcn_mfma_f32_16x16x32_bf16(aH, bH[nf], acc[mf][nf], 0, 0, 0);
        acc[mf][nf] = __builtin_amdgcn_mfma_f32_16x16x32_bf16(aH, bL[nf], acc[mf][nf], 0, 0, 0);
        acc[mf][nf] = __builtin_amdgcn_mfma_f32_16x16x32_bf16(aL, bH[nf], acc[mf][nf], 0, 0, 0);
      }
    }
    __syncthreads();
  }

#pragma unroll
  for (int mf = 0; mf < 4; ++mf)
#pragma unroll
    for (int nf = 0; nf < 4; ++nf) {
      int col = w * 64 + nf * 16 + l15;
      int kg = col >> 3, kin = col & 7;
#pragma unroll
      for (int j = 0; j < 4; ++j) {
        float vv = fmaxf(acc[mf][nf][j], 0.0f);
        u.g2.A2[kg][mf * 16 + l4 * 4 + j][kin] = bf16_rn(vv);
      }
    }
  __syncthreads();

  f32x4 acc2[4];
#pragma unroll
  for (int i = 0; i < 4; ++i) acc2[i] = zf;
#pragma unroll
  for (int ks = 0; ks < 8; ++ks) {
    short8 a2 = *(const short8*)&u.g2.A2[ks * 4 + l4][w * 16 + l15][0];
#pragma unroll
    for (int nf2 = 0; nf2 < 4; ++nf2) {
      size_t bi = ((size_t)(ks * 4 + l4) * 64 + nf2 * 16 + l15) * 8;
      short8 b2 = *(const short8*)(W2F + bi);
      acc2[nf2] = __builtin_amdgcn_mfma_f32_16x16x32_bf16(a2, b2, acc2[nf2], 0, 0, 0);
    }
  }
#pragma unroll
  for (int nf2 = 0; nf2 < 4; ++nf2)
#pragma unroll
    for (int j = 0; j < 4; ++j) {
      int r = row0 + w * 16 + l4 * 4 + j;
      if (r < n) hout[(size_t)r * NCLS + nf2 * 16 + l15] = bf16_rn(acc2[nf2][j]);
    }
}

// ------------------------- SpMM: 8 lanes/edge, uint4 row-slices ------------------------
// lane = g*8+p : group g (edge within batch), part p (channels 8p..8p+7).
// Wave gathers 8 edges per instruction at 1KiB/instr; partial sums reduced by
// shfl_xor butterfly over the group dimension (offsets 8,16,32).
__device__ inline void gather_row8(const int* __restrict__ rowptr,
                                   const int2* __restrict__ ecw,
                                   const unsigned short* __restrict__ src,
                                   int wid, int p, int g, float s[8]) {
#pragma unroll
  for (int i = 0; i < 8; ++i) s[i] = 0.0f;
  int e0 = rowptr[wid], e1 = rowptr[wid + 1];
  for (int e = e0; e < e1; e += 16) {
    int eeA = e + g, eeB = e + 8 + g;
    int eA = (eeA < e1) ? eeA : (e1 - 1);
    int eB = (eeB < e1) ? eeB : (e1 - 1);
    int2 tA = ecw[eA];
    int2 tB = ecw[eB];
    uint4 hA = *(const uint4*)(src + (((size_t)tA.x) << 6) + (p << 3));
    uint4 hB = *(const uint4*)(src + (((size_t)tB.x) << 6) + (p << 3));
    float wA = (eeA < e1) ? __int_as_float(tA.y) : 0.0f;
    float wB = (eeB < e1) ? __int_as_float(tB.y) : 0.0f;
    s[0] = fmaf(wA, u2f_lo(hA.x), s[0]); s[1] = fmaf(wA, u2f_hi(hA.x), s[1]);
    s[2] = fmaf(wA, u2f_lo(hA.y), s[2]); s[3] = fmaf(wA, u2f_hi(hA.y), s[3]);
    s[4] = fmaf(wA, u2f_lo(hA.z), s[4]); s[5] = fmaf(wA, u2f_hi(hA.z), s[5]);
    s[6] = fmaf(wA, u2f_lo(hA.w), s[6]); s[7] = fmaf(wA, u2f_hi(hA.w), s[7]);
    s[0] = fmaf(wB, u2f_lo(hB.x), s[0]); s[1] = fmaf(wB, u2f_hi(hB.x), s[1]);
    s[2] = fmaf(wB, u2f_lo(hB.y), s[2]); s[3] = fmaf(wB, u2f_hi(hB.y), s[3]);
    s[4] = fmaf(wB, u2f_lo(hB.z), s[4]); s[5] = fmaf(wB, u2f_hi(hB.z), s[5]);
    s[6] = fmaf(wB, u2f_lo(hB.w), s[6]); s[7] = fmaf(wB, u2f_hi(hB.w), s[7]);
  }
#pragma unroll
  for (int i = 0; i < 8; ++i) {
    s[i] += __shfl_xor(s[i], 8, 64);
    s[i] += __shfl_xor(s[i], 16, 64);
    s[i] += __shfl_xor(s[i], 32, 64);
  }
}

__global__ void spmm_first(const int* __restrict__ rowptr, const int2* __restrict__ ecw,
                           const unsigned short* __restrict__ h, unsigned short* __restrict__ tx1,
                           float* __restrict__ acc, const float* __restrict__ cw, int n) {
  int wid = (blockIdx.x * blockDim.x + threadIdx.x) >> 6;
  int lane = threadIdx.x & 63;
  if (wid >= n) return;
  int p = lane & 7, g = lane >> 3;
  float s[8];
  gather_row8(rowptr, ecw, h, wid, p, g, s);
  if (g == 0) {
    size_t base = (size_t)wid * NCLS + (p << 3);
    uint4 hv = *(const uint4*)(h + base);
    float c0 = cw[0], c1 = cw[1];
    float4 a0, a1;
    a0.x = c0 * u2f_lo(hv.x) + c1 * s[0]; a0.y = c0 * u2f_hi(hv.x) + c1 * s[1];
    a0.z = c0 * u2f_lo(hv.y) + c1 * s[2]; a0.w = c0 * u2f_hi(hv.y) + c1 * s[3];
    a1.x = c0 * u2f_lo(hv.z) + c1 * s[4]; a1.y = c0 * u2f_hi(hv.z) + c1 * s[5];
    a1.z = c0 * u2f_lo(hv.w) + c1 * s[6]; a1.w = c0 * u2f_hi(hv.w) + c1 * s[7];
    *(float4*)(acc + base) = a0;
    *(float4*)(acc + base + 4) = a1;
    uint4 tw;
    tw.x = pack2(s[0], s[1]); tw.y = pack2(s[2], s[3]);
    tw.z = pack2(s[4], s[5]); tw.w = pack2(s[6], s[7]);
    *(uint4*)(tx1 + base) = tw;
  }
}

__global__ void spmm_step(const int* __restrict__ rowptr, const int2* __restrict__ ecw,
                          const unsigned short* __restrict__ curb,
                          const unsigned short* __restrict__ prevb,
                          unsigned short* __restrict__ nextb, float* __restrict__ acc,
                          const float* __restrict__ cw, int k, int last, int n) {
  int wid = (blockIdx.x * blockDim.x + threadIdx.x) >> 6;
  int lane = threadIdx.x & 63;
  if (wid >= n) return;
  int p = lane & 7, g = lane >> 3;
  float s[8];
  gather_row8(rowptr, ecw, curb, wid, p, g, s);
  if (g == 0) {
    size_t base = (size_t)wid * NCLS + (p << 3);
    uint4 pv = *(const uint4*)(prevb + base);
    float t[8];
    t[0] = 2.0f * s[0] - u2f_lo(pv.x); t[1] = 2.0f * s[1] - u2f_hi(pv.x);
    t[2] = 2.0f * s[2] - u2f_lo(pv.y); t[3] = 2.0f * s[3] - u2f_hi(pv.y);
    t[4] = 2.0f * s[4] - u2f_lo(pv.z); t[5] = 2.0f * s[5] - u2f_hi(pv.z);
    t[6] = 2.0f * s[6] - u2f_lo(pv.w); t[7] = 2.0f * s[7] - u2f_hi(pv.w);
    float ck = cw[k];
    if (!last) {
      uint4 nw;
      nw.x = pack2(t[0], t[1]); nw.y = pack2(t[2], t[3]);
      nw.z = pack2(t[4], t[5]); nw.w = pack2(t[6], t[7]);
      *(uint4*)(nextb + base) = nw;
      float4 a0 = *(const float4*)(acc + base);
      float4 a1 = *(const float4*)(acc + base + 4);
      a0.x = fmaf(ck, t[0], a0.x); a0.y = fmaf(ck, t[1], a0.y);
      a0.z = fmaf(ck, t[2], a0.z); a0.w = fmaf(ck, t[3], a0.w);
      a1.x = fmaf(ck, t[4], a1.x); a1.y = fmaf(ck, t[5], a1.y);
      a1.z = fmaf(ck, t[6], a1.z); a1.w = fmaf(ck, t[7], a1.w);
      *(float4*)(acc + base) = a0;
      *(float4*)(acc + base + 4) = a1;
    } else {
      float4 a0 = *(const float4*)(acc + base);
      float4 a1 = *(const float4*)(acc + base + 4);
      float v[8];
      v[0] = fmaf(ck, t[0], a0.x); v[1] = fmaf(ck, t[1], a0.y);
      v[2] = fmaf(ck, t[2], a0.z); v[3] = fmaf(ck, t[3], a0.w);
      v[4] = fmaf(ck, t[4], a1.x); v[5] = fmaf(ck, t[5], a1.y);
      v[6] = fmaf(ck, t[6], a1.z); v[7] = fmaf(ck, t[7], a1.w);
      float m = v[0];
#pragma unroll
      for (int i = 1; i < 8; ++i) m = fmaxf(m, v[i]);
      m = fmaxf(m, __shfl_xor(m, 1, 64));
      m = fmaxf(m, __shfl_xor(m, 2, 64));
      m = fmaxf(m, __shfl_xor(m, 4, 64));
      float ss = 0.0f;
#pragma unroll
      for (int i = 0; i < 8; ++i) ss += expf(v[i] - m);
      ss += __shfl_xor(ss, 1, 64);
      ss += __shfl_xor(ss, 2, 64);
      ss += __shfl_xor(ss, 4, 64);
      float lg = m + logf(ss);
      float4 o0, o1;
      o0.x = v[0] - lg; o0.y = v[1] - lg; o0.z = v[2] - lg; o0.w = v[3] - lg;
      o1.x = v[4] - lg; o1.y = v[5] - lg; o1.z = v[6] - lg; o1.w = v[7] - lg;
      *(float4*)(acc + base) = o0;
      *(float4*)(acc + base + 4) = o1;
    }
  }
}

// ------------------------- launch -------------------------
extern "C" void kernel_launch(void* const* d_in, const int* in_sizes, int n_in,
                              void* d_out, int out_size, void* d_ws, size_t ws_size,
                              hipStream_t stream) {
  const float* x  = (const float*)d_in[0];
  const int*   ei = (const int*)d_in[1];
  const float* W1 = (const float*)d_in[2];
  const float* W2 = (const float*)d_in[3];
  const float* cw = (const float*)d_in[4];
  float* out = (float*)d_out;

  const int n = in_sizes[0] / NFEAT;     // 100000
  const int E = in_sizes[1] / 2;         // 1600000

  size_t off = 0;
  auto alloc = [&](size_t bytes) { size_t o = off; off += (bytes + 255) & ~(size_t)255; return o; };
  char* w = (char*)d_ws;
  size_t o_deg   = alloc((size_t)n * 4);
  size_t o_cnt   = alloc((size_t)n * 4);
  size_t o_cur   = alloc((size_t)n * 4);
  size_t o_dinv  = alloc((size_t)n * 4);
  size_t o_rp    = alloc((size_t)(n + 1) * 4);
  size_t o_bs    = alloc(4096 * 4);
  size_t o_w1fh  = alloc((size_t)KPAD * NHID * 2);
  size_t o_w1fl  = alloc((size_t)KPAD * NHID * 2);
  size_t o_w2f   = alloc((size_t)NHID * NCLS * 2);
  size_t o_ecw   = alloc((size_t)E * 8);
  size_t o_bufH  = alloc((size_t)n * NCLS * 2);
  size_t o_bufA  = alloc((size_t)n * NCLS * 2);
  size_t o_bufB  = alloc((size_t)n * NCLS * 2);

  int*   deg    = (int*)(w + o_deg);
  int*   cnt    = (int*)(w + o_cnt);
  int*   curi   = (int*)(w + o_cur);
  float* dinv   = (float*)(w + o_dinv);
  int*   rowptr = (int*)(w + o_rp);
  int*   bsums  = (int*)(w + o_bs);
  unsigned short* W1Fh = (unsigned short*)(w + o_w1fh);
  unsigned short* W1Fl = (unsigned short*)(w + o_w1fl);
  unsigned short* W2F  = (unsigned short*)(w + o_w2f);
  int2*  ecw    = (int2*)(w + o_ecw);
  unsigned short* bufH = (unsigned short*)(w + o_bufH);
  unsigned short* bufA = (unsigned short*)(w + o_bufA);
  unsigned short* bufB = (unsigned short*)(w + o_bufB);

  hipMemsetAsync(w + o_deg, 0, o_dinv - o_deg, stream);

  const int nb = (n + 255) / 256;

  conv_w1f<<<(KPAD * NHID + 255) / 256, 256, 0, stream>>>(W1, W1Fh, W1Fl);
  conv_w2f<<<(NHID * NCLS + 255) / 256, 256, 0, stream>>>(W2, W2F);

  edge_count<<<1024, 256, 0, stream>>>(ei, E, deg, cnt);
  make_dinv<<<nb, 256, 0, stream>>>(deg, dinv, n);
  scan_block<<<nb, 256, 0, stream>>>(cnt, rowptr, bsums, n);
  scan_sums<<<1, 1, 0, stream>>>(bsums, nb, rowptr);
  scan_add<<<nb, 256, 0, stream>>>(rowptr, bsums, n);
  scatter_edges<<<1024, 256, 0, stream>>>(ei, E, dinv, rowptr, curi, ecw);

  mlp_mfma<<<(n + 63) / 64, 256, 0, stream>>>(x, W1Fh, W1Fl, W2F, bufH, n);

  const int spmm_blocks = (n + 3) / 4;   // 4 waves per 256-thread block
  spmm_first<<<spmm_blocks, 256, 0, stream>>>(rowptr, ecw, bufH, bufA, out, cw, n);

  unsigned short* P = bufH;
  unsigned short* C = bufA;
  unsigned short* N = bufB;
  for (int k = 2; k <= KPOLY; ++k) {
    spmm_step<<<spmm_blocks, 256, 0, stream>>>(rowptr, ecw, C, P, N, out, cw, k,
                                               (k == KPOLY) ? 1 : 0, n);
    unsigned short* t = P; P = C; C = N; N = t;
  }
}